// Round 7
// baseline (415.595 us; speedup 1.0000x reference)
//
#include <hip/hip_runtime.h>
#include <math.h>

// Problem constants: y is (8, 3, 256, 512) fp32, lmbd is (1,3).
#define TVW 512      // row length
#define TVC 3        // channels; channel = (row >> 8) % 3
#define WPB 2        // waves (= rows) per block; block = 128
#define BLOCK (WPB * 64)
#define XROW (TVW + 6)   // pairs per row incl. 6 pad pairs (= x[511], matches ref clamp)
#define RTN 520

typedef float v2 __attribute__((ext_vector_type(2)));

// Round-4 structure (one row per wave, fully redundant lanes, lean SALU-framed
// inner loop + cold jump/boundary paths) upgraded with a PACKED-fp32 state
// machine: U=(umin,-umax), V=(vmin,-vmax), LDS stores (x,-x) pairs so the two
// Condat chains become symmetric and compile to v_pk_add/f ma_f32 (2x/inst).
// Jump test collapses to one v_min+v_cmp; hit updates sit behind a uniform
// ballot branch. Inner loop unrolled x2 with 2-deep register pipeline; pad
// pairs kill all per-iteration clamps. Output built in LDS, float4 writeback.
__global__ __launch_bounds__(BLOCK)
void tv1d_pk_kernel(const float* __restrict__ y,
                    const float* __restrict__ lmbd,
                    float* __restrict__ out,
                    int total_rows) {
    __shared__ __align__(16) v2 xs2[WPB * XROW];   // (x,-x) pairs, read-only
    __shared__ __align__(16) float ob[WPB * TVW];  // output rows
    __shared__ float rtab[RTN];                    // rtab[i] = 1/i
    const int tid  = threadIdx.x;
    const int wave = tid >> 6;
    const int lane = tid & 63;
    const int base_row = blockIdx.x * WPB;

    // ---- stage rows as (x,-x) pairs (two float4 stores per float4 load) ----
    {
        const float4* s4 = (const float4*)(y + (size_t)base_row * TVW);
        #pragma unroll
        for (int i = tid; i < WPB * TVW / 4; i += BLOCK) {
            float4 v = s4[i];
            const int r = i >> 7;                  // 128 float4 per row
            const int cpair = (i & 127) << 2;
            float4* dst = (float4*)(xs2 + r * XROW + cpair);
            dst[0] = make_float4(v.x, -v.x, v.y, -v.y);
            dst[1] = make_float4(v.z, -v.z, v.w, -v.w);
        }
        if (tid < WPB) {                           // pads = last element (ref clamp)
            const float last = y[(size_t)(base_row + tid) * TVW + (TVW - 1)];
            v2 p; p.x = last; p.y = -last;
            for (int j = 0; j < 6; ++j) xs2[tid * XROW + TVW + j] = p;
        }
        for (int i = tid; i < RTN; i += BLOCK)
            rtab[i] = 1.0f / (float)(i == 0 ? 1 : i);
    }
    __syncthreads();

    {
        const int row = base_row + wave;
        float lam = log1pf(expf(lmbd[(row >> 8) % TVC]));
        lam = __uint_as_float(__builtin_amdgcn_readfirstlane(__float_as_uint(lam)));
        const float nl = -lam;
        const float twol = 2.0f * lam;
        v2 lamp; lamp.x = lam; lamp.y = lam;
        const v2* x2 = xs2 + wave * XROW;
        float* o = ob + wave * TVW;

        // Condat state, packed: U=(umin,-umax), V=(vmin,-vmax).
        int k0 = 0, km = 0, kp = 0;
        v2 U = lamp;
        v2 V = x2[0] - lamp;   // (x0-lam, -x0-lam) = (vmin, -vmax)

        for (int guard = 0; guard < 4096; ++guard) {
            int trips_v = (TVW - 1) - k0; if (trips_v < 0) trips_v = 0;
            const int trips = __builtin_amdgcn_readfirstlane(trips_v);

            // 2-deep register pipeline: ynA=x[k0+1+t], ynB=x[k0+2+t] (pairs)
            v2 ynA = x2[k0 + 1];
            v2 ynB = x2[k0 + 2];
            float rnA = rtab[2];
            float rnB = rtab[3];
            const v2* xpp = x2 + (k0 + 3);
            const float* rpp = rtab + 4;
            const int kb = k0 + 1;

            v2 T = U;
            bool jumped = false;
            int t = 0;

// one extend step at trip (t+TOFF); consumes YN/RN, refills for trip+2
#define EXT_HALF(YN, RN, TOFF)                                              \
            {                                                               \
                const v2 pf = xpp[t + TOFF];                                \
                const float rf = rpp[t + TOFF];                             \
                T = (U - V) + YN;                                           \
                if (__ballot(fminf(T.x, T.y) < nl)) { jumped = true; break; } \
                if (__ballot((T.x >= lam) | (T.y >= lam))) {                \
                    v2 M; M.x = fmaxf(T.x, lam); M.y = fmaxf(T.y, lam);     \
                    V = V + (M - lamp) * RN;                                \
                    const int kc = kb + t + TOFF;                           \
                    km = (T.x >= lam) ? kc : km;                            \
                    kp = (T.y >= lam) ? kc : kp;                            \
                    U.x = fminf(T.x, lam); U.y = fminf(T.y, lam);           \
                } else {                                                    \
                    U = T;                                                  \
                }                                                           \
                YN = pf; RN = rf;                                           \
            }

            while (t + 1 < trips) {
                EXT_HALF(ynA, rnA, 0)
                EXT_HALF(ynB, rnB, 1)
                t += 2;
            }
            if (!jumped && t < trips) {
                do { EXT_HALF(ynA, rnA, 0) } while (0);   // tail (break-safe)
            }
#undef EXT_HALF

            if (jumped) {
                // ---- mid-row jump (b1/b2): flush and restart ----
                const bool negj = (T.x < nl);              // neg has priority
                const int e = negj ? km : kp;
                const float fv = negj ? V.x : -V.y;
                const int pe = e < TVW - 1 ? e : TVW - 1;
                for (int p = k0 + lane; p <= pe; p += 64) o[p] = fv;
                const int k0n = e + 1;
                v2 Vn = x2[k0n < XROW ? k0n : XROW - 1];   // pads cover k0n<=W+1
                if (negj) Vn.y -= twol; else Vn.x -= twol; // b1: vmax=v+2l; b2: vmin=v-2l
                V = Vn;
                U = lamp;
                km = kp = k0 = k0n;
            } else {
                // ---- boundary (k == W-1): a1 / a2 / terminate ----
                if (U.x < 0.0f) {                          // a1: umin < 0
                    const int pe = km < TVW - 1 ? km : TVW - 1;
                    for (int p = k0 + lane; p <= pe; p += 64) o[p] = V.x;
                    const int k0n = km + 1;
                    const v2 p2 = x2[k0n < XROW ? k0n : XROW - 1];
                    U.x = lam;
                    U.y = p2.y - lam - V.y;   // -(vmin' + lam - vmax_old)
                    V.x = p2.x;               // vmax, kp kept
                    km = k0 = k0n;
                } else if (U.y < 0.0f) {                   // a2: umax > 0
                    const int pe = kp < TVW - 1 ? kp : TVW - 1;
                    for (int p = k0 + lane; p <= pe; p += 64) o[p] = -V.y;
                    const int k0n = kp + 1;
                    const v2 p2 = x2[k0n < XROW ? k0n : XROW - 1];
                    U.y = lam;
                    U.x = p2.x - lam - V.x;   // vmax' - lam - vmin_old
                    V.y = p2.y;               // vmin, km kept
                    kp = k0 = k0n;
                } else {                                   // a3: terminate
                    const float v = V.x + U.x * rtab[trips + 1];
                    for (int p = k0 + lane; p < TVW; p += 64) o[p] = v;
                    break;
                }
            }
        }
    }
    __syncthreads();

    // ---- coalesced float4 writeback ob -> out ----
    {
        float4* d4 = (float4*)(out + (size_t)base_row * TVW);
        const float4* s4 = (const float4*)ob;
        #pragma unroll
        for (int i = tid; i < WPB * TVW / 4; i += BLOCK)
            d4[i] = s4[i];
    }
}

extern "C" void kernel_launch(void* const* d_in, const int* in_sizes, int n_in,
                              void* d_out, int out_size, void* d_ws, size_t ws_size,
                              hipStream_t stream) {
    const float* y    = (const float*)d_in[0];
    const float* lmbd = (const float*)d_in[1];
    float* out = (float*)d_out;

    const int total_rows = in_sizes[0] / TVW;              // 6144
    const int grid = (total_rows + WPB - 1) / WPB;         // 3072 blocks
    tv1d_pk_kernel<<<grid, BLOCK, 0, stream>>>(y, lmbd, out, total_rows);
}

// Round 8
// 406.828 us; speedup vs baseline: 1.0215x; 1.0215x over previous
//
#include <hip/hip_runtime.h>
#include <math.h>

// Problem constants: y is (8, 3, 256, 512) fp32, lmbd is (1,3).
#define TVW 512      // row length
#define TVC 3        // channels; channel = (row >> 8) % 3
#define WPB 2        // waves (= rows) per block; block = 128
#define BLOCK (WPB * 64)
#define XROW (TVW + 8)   // (x,-x) pairs per row incl. 8 pad pairs (= x[511], ref clamp)
#define RTN 520

typedef float v2 __attribute__((ext_vector_type(2)));

// Round-4 skeleton (one row per wave, redundant lanes, SALU-framed extend loop
// with a SINGLE ballot per step, cold jump/boundary paths) + packed fp32 state:
// U=(umin,-umax), V=(vmin,-vmax), LDS holds (x,-x) pairs so both Condat chains
// share pk_add/pk_fma/pk_min/pk_max instructions. Hit updates are branchless
// and unconditional (hits fire ~80% of steps in this data regime -- gating
// them was round 7's mistake). rtab stored as pairs to avoid splats. Staging
// uses scalar global loads + b64 pair stores (4-way bank alias only).
__global__ __launch_bounds__(BLOCK)
void tv1d_pk4_kernel(const float* __restrict__ y,
                     const float* __restrict__ lmbd,
                     float* __restrict__ out,
                     int total_rows) {
    __shared__ __align__(16) v2 xs2[WPB * XROW];   // (x,-x) pairs, read-only
    __shared__ __align__(16) v2 rtab2[RTN];        // (1/i, 1/i)
    __shared__ __align__(16) float ob[WPB * TVW];  // output rows
    const int tid  = threadIdx.x;
    const int wave = tid >> 6;
    const int lane = tid & 63;
    const int base_row = blockIdx.x * WPB;

    // ---- stage: coalesced scalar loads, lane-contiguous b64 pair stores ----
    {
        const float* src = y + (size_t)base_row * TVW;
        #pragma unroll
        for (int e = tid; e < WPB * TVW; e += BLOCK) {
            const float v = src[e];
            const int r = e >> 9, c = e & 511;
            v2 p; p.x = v; p.y = -v;
            xs2[r * XROW + c] = p;
        }
        if (tid < WPB * 8) {     // pads = last element (ref's min(idx,W-1) clamp)
            const int r = tid >> 3, j = tid & 7;
            const float last = y[(size_t)(base_row + r) * TVW + (TVW - 1)];
            v2 p; p.x = last; p.y = -last;
            xs2[r * XROW + TVW + j] = p;
        }
        for (int i = tid; i < RTN; i += BLOCK) {
            const float rv = 1.0f / (float)(i == 0 ? 1 : i);
            v2 p; p.x = rv; p.y = rv;
            rtab2[i] = p;
        }
    }
    __syncthreads();

    {
        const int row = base_row + wave;
        float lam = log1pf(expf(lmbd[(row >> 8) % TVC]));
        lam = __uint_as_float(__builtin_amdgcn_readfirstlane(__float_as_uint(lam)));
        const float nl = -lam;
        const float twol = 2.0f * lam;
        v2 lamp; lamp.x = lam; lamp.y = lam;
        const v2* x2 = xs2 + wave * XROW;
        float* o = ob + wave * TVW;

        // Packed Condat state: U=(umin,-umax), V=(vmin,-vmax)  [validated r7]
        int k0 = 0, km = 0, kp = 0;
        v2 U = lamp;
        v2 V = x2[0] - lamp;     // (x0-lam, -x0-lam)

        for (int guard = 0; guard < 4096; ++guard) {
            int trips_v = (TVW - 1) - k0; if (trips_v < 0) trips_v = 0;
            const int trips = __builtin_amdgcn_readfirstlane(trips_v);

            // 2-deep register pipeline over (x,-x) pairs and recip pairs
            v2 ynA = x2[k0 + 1];
            v2 ynB = x2[k0 + 2];
            v2 rnA = rtab2[2];
            v2 rnB = rtab2[3];
            const v2* xpp = x2 + (k0 + 3);
            const v2* rpp = rtab2 + 4;
            const int kb = k0 + 1;

            v2 T = U;
            bool jumped = false;
            int t = 0;

// one extend step at trip (t+TOFF): SINGLE ballot, branchless hit updates
#define EXT_STEP(YN, RN, TOFF)                                              \
            {                                                               \
                const v2 pf = xpp[t + TOFF];                                \
                const v2 rf = rpp[t + TOFF];                                \
                T = (U - V) + YN;                                           \
                if (__ballot(fminf(T.x, T.y) < nl)) { jumped = true; break; } \
                const v2 M = __builtin_elementwise_max(T, lamp);            \
                V = __builtin_elementwise_fma(M - lamp, RN, V);             \
                const int kc = kb + t + TOFF;                               \
                km = (T.x >= lam) ? kc : km;                                \
                kp = (T.y >= lam) ? kc : kp;                                \
                U = __builtin_elementwise_min(T, lamp);                     \
                YN = pf; RN = rf;                                           \
            }

            while (t + 1 < trips) {
                EXT_STEP(ynA, rnA, 0)
                EXT_STEP(ynB, rnB, 1)
                t += 2;
            }
            if (!jumped && t < trips) {
                do { EXT_STEP(ynA, rnA, 0) } while (0);   // tail (break-safe)
            }
#undef EXT_STEP

            if (jumped) {
                // ---- mid-row jump (b1/b2): flush and restart ----
                const bool negj = (T.x < nl);              // neg has priority
                const int e = negj ? km : kp;
                const float fv = negj ? V.x : -V.y;
                for (int p = k0 + lane; p <= e; p += 64) o[p] = fv;
                const int k0n = e + 1;                     // <= W-1 mid-row
                v2 Vn = x2[k0n];
                if (negj) Vn.y -= twol; else Vn.x -= twol; // b1: vmax=v+2l; b2: vmin=v-2l
                V = Vn;
                U = lamp;
                km = kp = k0 = k0n;
            } else {
                // ---- boundary (k == W-1): a1 / a2 / terminate ----
                if (U.x < 0.0f) {                          // a1: umin < 0
                    const int pe = km < TVW - 1 ? km : TVW - 1;
                    for (int p = k0 + lane; p <= pe; p += 64) o[p] = V.x;
                    const int k0n = km + 1;                // <= W; pads cover
                    const v2 p2 = x2[k0n];
                    U.x = lam;
                    U.y = p2.y - lam - V.y;   // -(vmin' + lam - vmax_old)
                    V.x = p2.x;               // vmax, kp kept
                    km = k0 = k0n;
                } else if (U.y < 0.0f) {                   // a2: umax > 0
                    const int pe = kp < TVW - 1 ? kp : TVW - 1;
                    for (int p = k0 + lane; p <= pe; p += 64) o[p] = -V.y;
                    const int k0n = kp + 1;
                    const v2 p2 = x2[k0n];
                    U.y = lam;
                    U.x = p2.x - lam - V.x;   // vmax' - lam - vmin_old
                    V.y = p2.y;               // vmin, km kept
                    kp = k0 = k0n;
                } else {                                   // a3: terminate
                    const float v = V.x + U.x * rtab2[trips + 1].x;
                    for (int p = k0 + lane; p < TVW; p += 64) o[p] = v;
                    break;
                }
            }
        }
    }
    __syncthreads();

    // ---- coalesced float4 writeback ob -> out ----
    {
        float4* d4 = (float4*)(out + (size_t)base_row * TVW);
        const float4* s4 = (const float4*)ob;
        #pragma unroll
        for (int i = tid; i < WPB * TVW / 4; i += BLOCK)
            d4[i] = s4[i];
    }
}

extern "C" void kernel_launch(void* const* d_in, const int* in_sizes, int n_in,
                              void* d_out, int out_size, void* d_ws, size_t ws_size,
                              hipStream_t stream) {
    const float* y    = (const float*)d_in[0];
    const float* lmbd = (const float*)d_in[1];
    float* out = (float*)d_out;

    const int total_rows = in_sizes[0] / TVW;              // 6144
    const int grid = (total_rows + WPB - 1) / WPB;         // 3072 blocks
    tv1d_pk4_kernel<<<grid, BLOCK, 0, stream>>>(y, lmbd, out, total_rows);
}